// Round 5
// baseline (566.461 us; speedup 1.0000x reference)
//
#include <hip/hip_runtime.h>

#define CD 1024
#define NB 4096

typedef __attribute__((ext_vector_type(8))) short short8;
typedef __attribute__((ext_vector_type(4))) short short4v;
typedef __attribute__((ext_vector_type(4))) float f32x4;
typedef __attribute__((ext_vector_type(4))) int int4v;

typedef __attribute__((address_space(1))) const void gv_t;
typedef __attribute__((address_space(3))) void lv_t;
#define GLOAD16(g, l) __builtin_amdgcn_global_load_lds((gv_t*)(g), (lv_t*)(l), 16, 0, 0)

__device__ __forceinline__ short f2bf(float f) {
  unsigned u = __float_as_uint(f);
  u = (u + 0x7FFFu + ((u >> 16) & 1u)) >> 16;
  return (short)u;
}
__device__ __forceinline__ float bf2f(short s) {
  return __uint_as_float(((unsigned)(unsigned short)s) << 16);
}

// ---- fused: x f32->bf16 (blocks 0..2047) + dequant12+LoRA-fold (blocks 2048..8191) ----
__global__ __launch_bounds__(256) void prep_kernel(const float* __restrict__ x,
                                                   short* __restrict__ xb,
                                                   const int* __restrict__ q4,
                                                   const float* __restrict__ nrm,
                                                   const float* __restrict__ la,
                                                   const float* __restrict__ lb,
                                                   short* __restrict__ Wb) {
  int bid = blockIdx.x;
  if (bid < 2048) {
    int i = (bid * 256 + threadIdx.x) * 8;
    f32x4 a = *(const f32x4*)(x + i);
    f32x4 b = *(const f32x4*)(x + i + 4);
    short8 o;
    o[0] = f2bf(a[0]); o[1] = f2bf(a[1]); o[2] = f2bf(a[2]); o[3] = f2bf(a[3]);
    o[4] = f2bf(b[0]); o[5] = f2bf(b[1]); o[6] = f2bf(b[2]); o[7] = f2bf(b[3]);
    *(short8*)(xb + i) = o;
    return;
  }
  int tidg = (bid - 2048) * 256 + threadIdx.x;
  int w0 = tidg * 4;
  int l = w0 >> 19;
  int wl = w0 & 524287;
  int g = wl >> 6;
  int j0 = wl & 63;
  int o = g >> 3;
  int kb = ((g & 7) << 7) + (j0 << 1);
  int4v q = *(const int4v*)(q4 + w0);
  float n = nrm[(l << 13) + g];
  float s = n * (2.0f / 15.0f);
  f32x4 B = *(const f32x4*)(lb + (((l << 10) + o) << 2));
  const float* A = la + (l << 12);
  float Ar[4][8];
#pragma unroll
  for (int r = 0; r < 4; ++r) {
    f32x4 u = *(const f32x4*)(A + r * CD + kb);
    f32x4 v = *(const f32x4*)(A + r * CD + kb + 4);
    Ar[r][0] = u[0]; Ar[r][1] = u[1]; Ar[r][2] = u[2]; Ar[r][3] = u[3];
    Ar[r][4] = v[0]; Ar[r][5] = v[1]; Ar[r][6] = v[2]; Ar[r][7] = v[3];
  }
  short8 outv;
#pragma unroll
  for (int p = 0; p < 8; ++p) {
    int qw = q[p >> 1];
    int nib = (qw >> ((p & 1) << 2)) & 15;
    float wv = (float)nib * s - n;
    wv += B[0] * Ar[0][p] + B[1] * Ar[1][p] + B[2] * Ar[2][p] + B[3] * Ar[3][p];
    outv[p] = f2bf(wv);
  }
  *(short8*)(Wb + (l << 20) + (o << 10) + kb) = outv;
}

// ---- GEMM: out[M,O] = Act[M,K] @ W[O,K]^T, bf16 in, f32 acc ----
// Flatmm-style: W staged in LDS (3 bufs, 2-ahead, counted vmcnt(10) — never 0
// mid-loop); Act streamed global->regs, double-buffered, compiler-counted
// waits let Act loads fly across barriers. 512 thr = 8 waves (2/SIMD),
// wave-tile 64x32. Grid 256 = 1 block/CU; XCD patch swizzle (1MB Act + 2MB W
// per XCD L2). EPI: 0 = relu->bf16, 2 = +resid->bf16, 3 = +resid->f32
template <int EPI>
__global__ __launch_bounds__(512) void qgemm(const short* __restrict__ Act,
                                             const short* __restrict__ W,
                                             const short* __restrict__ Res,
                                             void* __restrict__ Out) {
  __shared__ __align__(16) short ldsW[3][128 * 64];
  const int tid = threadIdx.x;
  const int lane = tid & 63;
  const int wid = tid >> 6;
  const int wr = wid >> 2;                 // 0..1 : 64-row slice
  const int wc = wid & 3;                  // 0..3 : 32-col slice
  const int f = blockIdx.x;
  const int xcd = f & 7, c = f >> 3;
  const int m0 = (((xcd << 2) | (c & 3)) << 7);  // 32 M-tiles of 128
  const int o0 = ((c >> 2) << 7);                // 8 O-tiles of 128

  const int frow = lane & 15;
  const int fch = lane >> 4;               // 0..3

  // W staging source (pre-swizzled chunk ^= row&7; LDS dest linear per wave)
  const int swrow = tid >> 3;              // 0..63 (+64 for i=1)
  const short* wsrc0 = W + (long)(o0 + swrow) * CD + (((tid & 7) ^ (swrow & 7)) << 3);
  const short* wsrc1 = W + (long)(o0 + swrow + 64) * CD + (((tid & 7) ^ ((swrow + 64) & 7)) << 3);

  // Act fragment row pointers (per-lane): row = m0+(wr<<6)+(m<<4)+frow, +fch*8
  const short* arow[4];
#pragma unroll
  for (int m = 0; m < 4; ++m)
    arow[m] = Act + (long)(m0 + (wr << 6) + (m << 4) + frow) * CD + (fch << 3);

  f32x4 acc[4][2] = {};
  short8 afA[8], afB[8];

  auto stageW = [&](int T, int buf) {
    const int koff = T << 6;
    GLOAD16(wsrc0 + koff, &ldsW[buf][tid << 3]);
    GLOAD16(wsrc1 + koff, &ldsW[buf][(tid + 512) << 3]);
  };
  auto loadA = [&](int T, short8* dst) {
    const int c0 = T << 6;
#pragma unroll
    for (int kk = 0; kk < 2; ++kk)
#pragma unroll
      for (int m = 0; m < 4; ++m)
        dst[kk * 4 + m] = *(const short8*)(arow[m] + c0 + (kk << 5));
  };

  // prologue: W0, W1 staged; A0 -> afA.   Issue order: W0 W1 A0
  stageW(0, 0);
  stageW(1, 1);
  loadA(0, afA);

#pragma unroll
  for (int t = 0; t < 16; ++t) {
    short8* cur = (t & 1) ? afB : afA;
    short8* nxt = (t & 1) ? afA : afB;
    // newest-10 outstanding = A(t):8 + W(t+1):2  ->  vmcnt(10) retires W(t)
    if (t < 15) asm volatile("s_waitcnt vmcnt(10)" ::: "memory");
    else        asm volatile("s_waitcnt vmcnt(8)" ::: "memory");
    asm volatile("s_waitcnt lgkmcnt(0)" ::: "memory");
    __builtin_amdgcn_sched_barrier(0);
    __builtin_amdgcn_s_barrier();
    __builtin_amdgcn_sched_barrier(0);
    if (t + 1 < 16) loadA(t + 1, nxt);       // 8 reg loads (fly across barriers)
    __builtin_amdgcn_sched_barrier(0);
    if (t + 2 < 16) stageW(t + 2, (t + 2) % 3);  // 2 gload_lds
    __builtin_amdgcn_sched_barrier(0);
    const short* Lw = ldsW[t % 3];
#pragma unroll
    for (int kk = 0; kk < 2; ++kk) {
      short8 wf[2];
#pragma unroll
      for (int n = 0; n < 2; ++n) {
        int row = (wc << 5) + (n << 4) + frow;
        int ch = ((kk << 2) + fch) ^ (frow & 7);
        wf[n] = *(const short8*)(Lw + (row << 6) + (ch << 3));
      }
#pragma unroll
      for (int m = 0; m < 4; ++m)
#pragma unroll
        for (int n = 0; n < 2; ++n)
          acc[m][n] = __builtin_amdgcn_mfma_f32_16x16x32_bf16(wf[n], cur[kk * 4 + m], acc[m][n], 0, 0, 0);
    }
  }

  // epilogue: lane&15 = M-row, (lane>>4)*4+reg = out-col (verified mapping)
  const int orow = m0 + (wr << 6) + frow;
  const int ocol = o0 + (wc << 5) + (fch << 2);
#pragma unroll
  for (int m = 0; m < 4; ++m) {
#pragma unroll
    for (int n = 0; n < 2; ++n) {
      long row = orow + (m << 4);
      int col = ocol + (n << 4);
      f32x4 v = acc[m][n];
      if (EPI == 0) {
        short4v ov;
        ov[0] = f2bf(fmaxf(v[0], 0.0f));
        ov[1] = f2bf(fmaxf(v[1], 0.0f));
        ov[2] = f2bf(fmaxf(v[2], 0.0f));
        ov[3] = f2bf(fmaxf(v[3], 0.0f));
        *(short4v*)((short*)Out + row * CD + col) = ov;
      } else if (EPI == 2) {
        short4v rv = *(const short4v*)(Res + row * CD + col);
        short4v ov;
        ov[0] = f2bf(v[0] + bf2f(rv[0]));
        ov[1] = f2bf(v[1] + bf2f(rv[1]));
        ov[2] = f2bf(v[2] + bf2f(rv[2]));
        ov[3] = f2bf(v[3] + bf2f(rv[3]));
        *(short4v*)((short*)Out + row * CD + col) = ov;
      } else {
        short4v rv = *(const short4v*)(Res + row * CD + col);
        f32x4 ov;
        ov[0] = v[0] + bf2f(rv[0]);
        ov[1] = v[1] + bf2f(rv[1]);
        ov[2] = v[2] + bf2f(rv[2]);
        ov[3] = v[3] + bf2f(rv[3]);
        *(f32x4*)((float*)Out + row * CD + col) = ov;
      }
    }
  }
}

// ---- LayerNorm over rows of 1024 bf16 ----
__global__ __launch_bounds__(256) void ln_kernel(const short* __restrict__ in,
                                                 short* __restrict__ out,
                                                 const float* __restrict__ g,
                                                 const float* __restrict__ b) {
  __shared__ float rs_[4], rq_[4];
  int row = blockIdx.x, tid = threadIdx.x;
  int k = tid * 4;
  short4v v = *(const short4v*)(in + (long)row * CD + k);
  float f0 = bf2f(v[0]), f1 = bf2f(v[1]), f2 = bf2f(v[2]), f3 = bf2f(v[3]);
  float s = f0 + f1 + f2 + f3;
  float q = f0 * f0 + f1 * f1 + f2 * f2 + f3 * f3;
#pragma unroll
  for (int off = 1; off < 64; off <<= 1) {
    s += __shfl_xor(s, off);
    q += __shfl_xor(q, off);
  }
  if ((tid & 63) == 0) { rs_[tid >> 6] = s; rq_[tid >> 6] = q; }
  __syncthreads();
  s = rs_[0] + rs_[1] + rs_[2] + rs_[3];
  q = rq_[0] + rq_[1] + rq_[2] + rq_[3];
  float mu = s * (1.0f / 1024.0f);
  float var = q * (1.0f / 1024.0f) - mu * mu;
  float rstd = rsqrtf(var + 1e-5f);
  short4v o;
  o[0] = f2bf((f0 - mu) * rstd * g[k] + b[k]);
  o[1] = f2bf((f1 - mu) * rstd * g[k + 1] + b[k + 1]);
  o[2] = f2bf((f2 - mu) * rstd * g[k + 2] + b[k + 2]);
  o[3] = f2bf((f3 - mu) * rstd * g[k + 3] + b[k + 3]);
  *(short4v*)(out + (long)row * CD + k) = o;
}

extern "C" void kernel_launch(void* const* d_in, const int* in_sizes, int n_in,
                              void* d_out, int out_size, void* d_ws, size_t ws_size,
                              hipStream_t stream) {
  const float* x = (const float*)d_in[0];
  const int* q4 = (const int*)d_in[1];
  const float* nrm = (const float*)d_in[2];
  const float* la = (const float*)d_in[3];
  const float* lb = (const float*)d_in[4];
  const float* lng = (const float*)d_in[5];
  const float* lnb = (const float*)d_in[6];

  short* Wb = (short*)d_ws;                             // 24 MB: 12 x [1024][1024] bf16
  short* buf0 = (short*)((char*)d_ws + (24u << 20));    // 8 MB
  short* buf1 = buf0 + (long)NB * CD;                   // 8 MB
  short* buf2 = (short*)d_out;                          // d_out lower 8 MB as bf16 scratch
  short* buf3 = buf2 + (long)NB * CD;                   // d_out upper 8 MB
  float* outf = (float*)d_out;

  prep_kernel<<<dim3(8192), dim3(256), 0, stream>>>(x, buf0, q4, nrm, la, lb, Wb);

  dim3 gg(256), bb(512);
  auto Wl = [&](int l) { return Wb + ((long)l << 20); };

  // block 1 (input xb = buf0, resid buf0)
  qgemm<0><<<gg, bb, 0, stream>>>(buf0, Wl(0), nullptr, buf1);
  qgemm<0><<<gg, bb, 0, stream>>>(buf1, Wl(1), nullptr, buf2);
  qgemm<2><<<gg, bb, 0, stream>>>(buf2, Wl(2), buf0, buf3);
  ln_kernel<<<dim3(4096), dim3(256), 0, stream>>>(buf3, buf0, lng, lnb);
  // block 2 (input/resid buf0)
  qgemm<0><<<gg, bb, 0, stream>>>(buf0, Wl(3), nullptr, buf1);
  qgemm<0><<<gg, bb, 0, stream>>>(buf1, Wl(4), nullptr, buf2);
  qgemm<2><<<gg, bb, 0, stream>>>(buf2, Wl(5), buf0, buf3);
  // block 3 (input/resid buf3)
  qgemm<0><<<gg, bb, 0, stream>>>(buf3, Wl(6), nullptr, buf1);
  qgemm<0><<<gg, bb, 0, stream>>>(buf1, Wl(7), nullptr, buf2);
  qgemm<2><<<gg, bb, 0, stream>>>(buf2, Wl(8), buf3, buf0);
  ln_kernel<<<dim3(4096), dim3(256), 0, stream>>>(buf0, buf1, lng + CD, lnb + CD);
  // block 4 (input/resid buf1), final layer writes f32 to d_out
  qgemm<0><<<gg, bb, 0, stream>>>(buf1, Wl(9), nullptr, buf2);
  qgemm<0><<<gg, bb, 0, stream>>>(buf2, Wl(10), nullptr, buf0);
  qgemm<3><<<gg, bb, 0, stream>>>(buf0, Wl(11), buf1, (void*)outf);
}

// Round 6
// 317.480 us; speedup vs baseline: 1.7842x; 1.7842x over previous
//
#include <hip/hip_runtime.h>

#define CD 1024
#define NB 4096

typedef __attribute__((ext_vector_type(8))) short short8;
typedef __attribute__((ext_vector_type(4))) short short4v;
typedef __attribute__((ext_vector_type(4))) float f32x4;
typedef __attribute__((ext_vector_type(4))) int int4v;

typedef __attribute__((address_space(1))) const void gv_t;
typedef __attribute__((address_space(3))) void lv_t;
#define GLOAD16(g, l) __builtin_amdgcn_global_load_lds((gv_t*)(g), (lv_t*)(l), 16, 0, 0)

__device__ __forceinline__ short f2bf(float f) {
  unsigned u = __float_as_uint(f);
  u = (u + 0x7FFFu + ((u >> 16) & 1u)) >> 16;
  return (short)u;
}
__device__ __forceinline__ float bf2f(short s) {
  return __uint_as_float(((unsigned)(unsigned short)s) << 16);
}

// ---- fused: x f32->bf16 (blocks 0..2047) + dequant12+LoRA-fold (blocks 2048..8191) ----
__global__ __launch_bounds__(256) void prep_kernel(const float* __restrict__ x,
                                                   short* __restrict__ xb,
                                                   const int* __restrict__ q4,
                                                   const float* __restrict__ nrm,
                                                   const float* __restrict__ la,
                                                   const float* __restrict__ lb,
                                                   short* __restrict__ Wb) {
  int bid = blockIdx.x;
  if (bid < 2048) {
    int i = (bid * 256 + threadIdx.x) * 8;
    f32x4 a = *(const f32x4*)(x + i);
    f32x4 b = *(const f32x4*)(x + i + 4);
    short8 o;
    o[0] = f2bf(a[0]); o[1] = f2bf(a[1]); o[2] = f2bf(a[2]); o[3] = f2bf(a[3]);
    o[4] = f2bf(b[0]); o[5] = f2bf(b[1]); o[6] = f2bf(b[2]); o[7] = f2bf(b[3]);
    *(short8*)(xb + i) = o;
    return;
  }
  int tidg = (bid - 2048) * 256 + threadIdx.x;
  int w0 = tidg * 4;
  int l = w0 >> 19;
  int wl = w0 & 524287;
  int g = wl >> 6;
  int j0 = wl & 63;
  int o = g >> 3;
  int kb = ((g & 7) << 7) + (j0 << 1);
  int4v q = *(const int4v*)(q4 + w0);
  float n = nrm[(l << 13) + g];
  float s = n * (2.0f / 15.0f);
  f32x4 B = *(const f32x4*)(lb + (((l << 10) + o) << 2));
  const float* A = la + (l << 12);
  float Ar[4][8];
#pragma unroll
  for (int r = 0; r < 4; ++r) {
    f32x4 u = *(const f32x4*)(A + r * CD + kb);
    f32x4 v = *(const f32x4*)(A + r * CD + kb + 4);
    Ar[r][0] = u[0]; Ar[r][1] = u[1]; Ar[r][2] = u[2]; Ar[r][3] = u[3];
    Ar[r][4] = v[0]; Ar[r][5] = v[1]; Ar[r][6] = v[2]; Ar[r][7] = v[3];
  }
  short8 outv;
#pragma unroll
  for (int p = 0; p < 8; ++p) {
    int qw = q[p >> 1];
    int nib = (qw >> ((p & 1) << 2)) & 15;
    float wv = (float)nib * s - n;
    wv += B[0] * Ar[0][p] + B[1] * Ar[1][p] + B[2] * Ar[2][p] + B[3] * Ar[3][p];
    outv[p] = f2bf(wv);
  }
  *(short8*)(Wb + (l << 20) + (o << 10) + kb) = outv;
}

// ---- GEMM: out[M,O] = Act[M,K] @ W[O,K]^T, bf16 in, f32 acc ----
// BM=64, BN=128, BK=64; grid 512 = 2 blocks/CU (the R1 structure, re-split
// for cross-block latency overlap per m114). 4 waves, wave-tile 32x64.
// LDS 48KB double-buffered; simple 2-phase schedule (proven best so far).
// XCD map: mt=(xcd<<3)|(idx&7), ot=idx>>3 -> 1MB Act + 2MB W per XCD L2.
// EPI: 0 = relu->bf16, 2 = +resid->bf16, 3 = +resid->f32
template <int EPI>
__global__ __launch_bounds__(256) void qgemm(const short* __restrict__ Act,
                                             const short* __restrict__ W,
                                             const short* __restrict__ Res,
                                             void* __restrict__ Out) {
  __shared__ __align__(16) short ldsA[2][64 * 64];
  __shared__ __align__(16) short ldsB[2][128 * 64];
  const int tid = threadIdx.x;
  const int lane = tid & 63;
  const int wid = tid >> 6;
  const int wr = wid >> 1, wc = wid & 1;   // wave-tile 32 rows x 64 cols
  const int f = blockIdx.x;
  const int xcd = f & 7, idx = f >> 3;     // 64 per XCD
  const int m0 = ((xcd << 3) | (idx & 7)) << 6;  // 64 M-tiles of 64
  const int o0 = (idx >> 3) << 7;                // 8 O-tiles of 128

  // staging (source pre-swizzled chunk ^= row&7; LDS linear):
  // A: 512 chunks (64rx8c), threads handle c = tid, tid+256
  // B: 1024 chunks (128rx8c), c = tid, tid+256, tid+512, tid+768
  const short* asrc[2];
  const short* bsrc[4];
#pragma unroll
  for (int i = 0; i < 2; ++i) {
    int c = tid + (i << 8);
    int row = c >> 3;
    asrc[i] = Act + (long)(m0 + row) * CD + (((c & 7) ^ (row & 7)) << 3);
  }
#pragma unroll
  for (int i = 0; i < 4; ++i) {
    int c = tid + (i << 8);
    int row = c >> 3;
    bsrc[i] = W + (long)(o0 + row) * CD + (((c & 7) ^ (row & 7)) << 3);
  }

  auto stage = [&](int t, int buf) {
    const int koff = t << 6;
#pragma unroll
    for (int i = 0; i < 2; ++i)
      GLOAD16(asrc[i] + koff, &ldsA[buf][(tid + (i << 8)) << 3]);
#pragma unroll
    for (int i = 0; i < 4; ++i)
      GLOAD16(bsrc[i] + koff, &ldsB[buf][(tid + (i << 8)) << 3]);
  };

  f32x4 acc[2][4] = {};
  const int frow = lane & 15;
  const int fch = lane >> 4;               // 0..3
  const int fsw = lane & 7;

  stage(0, 0);
  for (int t = 0; t < 16; ++t) {
    __syncthreads();                       // buf[t&1] staged (drains vmcnt)
    if (t < 15) stage(t + 1, (t + 1) & 1);
    const short* La = ldsA[t & 1];
    const short* Lb = ldsB[t & 1];
#pragma unroll
    for (int kk = 0; kk < 2; ++kk) {
      const int chsw = ((kk << 2) + fch) ^ fsw;
      short8 af[2], wf[4];
#pragma unroll
      for (int m = 0; m < 2; ++m) {
        int row = (wr << 5) + (m << 4) + frow;
        af[m] = *(const short8*)(La + (row << 6) + (chsw << 3));
      }
#pragma unroll
      for (int n = 0; n < 4; ++n) {
        int row = (wc << 6) + (n << 4) + frow;
        wf[n] = *(const short8*)(Lb + (row << 6) + (chsw << 3));
      }
#pragma unroll
      for (int m = 0; m < 2; ++m)
#pragma unroll
        for (int n = 0; n < 4; ++n)
          acc[m][n] = __builtin_amdgcn_mfma_f32_16x16x32_bf16(wf[n], af[m], acc[m][n], 0, 0, 0);
    }
  }

  // epilogue (swapped operands): lane&15 = M-row, (lane>>4)*4+reg = out-col
  const int orow = m0 + (wr << 5) + frow;
  const int ocol = o0 + (wc << 6) + (fch << 2);
#pragma unroll
  for (int m = 0; m < 2; ++m) {
#pragma unroll
    for (int n = 0; n < 4; ++n) {
      long row = orow + (m << 4);
      int col = ocol + (n << 4);
      f32x4 v = acc[m][n];
      if (EPI == 0) {
        short4v ov;
        ov[0] = f2bf(fmaxf(v[0], 0.0f));
        ov[1] = f2bf(fmaxf(v[1], 0.0f));
        ov[2] = f2bf(fmaxf(v[2], 0.0f));
        ov[3] = f2bf(fmaxf(v[3], 0.0f));
        *(short4v*)((short*)Out + row * CD + col) = ov;
      } else if (EPI == 2) {
        short4v rv = *(const short4v*)(Res + row * CD + col);
        short4v ov;
        ov[0] = f2bf(v[0] + bf2f(rv[0]));
        ov[1] = f2bf(v[1] + bf2f(rv[1]));
        ov[2] = f2bf(v[2] + bf2f(rv[2]));
        ov[3] = f2bf(v[3] + bf2f(rv[3]));
        *(short4v*)((short*)Out + row * CD + col) = ov;
      } else {
        short4v rv = *(const short4v*)(Res + row * CD + col);
        f32x4 ov;
        ov[0] = v[0] + bf2f(rv[0]);
        ov[1] = v[1] + bf2f(rv[1]);
        ov[2] = v[2] + bf2f(rv[2]);
        ov[3] = v[3] + bf2f(rv[3]);
        *(f32x4*)((float*)Out + row * CD + col) = ov;
      }
    }
  }
}

// ---- LayerNorm over rows of 1024 bf16 ----
__global__ __launch_bounds__(256) void ln_kernel(const short* __restrict__ in,
                                                 short* __restrict__ out,
                                                 const float* __restrict__ g,
                                                 const float* __restrict__ b) {
  __shared__ float rs_[4], rq_[4];
  int row = blockIdx.x, tid = threadIdx.x;
  int k = tid * 4;
  short4v v = *(const short4v*)(in + (long)row * CD + k);
  float f0 = bf2f(v[0]), f1 = bf2f(v[1]), f2 = bf2f(v[2]), f3 = bf2f(v[3]);
  float s = f0 + f1 + f2 + f3;
  float q = f0 * f0 + f1 * f1 + f2 * f2 + f3 * f3;
#pragma unroll
  for (int off = 1; off < 64; off <<= 1) {
    s += __shfl_xor(s, off);
    q += __shfl_xor(q, off);
  }
  if ((tid & 63) == 0) { rs_[tid >> 6] = s; rq_[tid >> 6] = q; }
  __syncthreads();
  s = rs_[0] + rs_[1] + rs_[2] + rs_[3];
  q = rq_[0] + rq_[1] + rq_[2] + rq_[3];
  float mu = s * (1.0f / 1024.0f);
  float var = q * (1.0f / 1024.0f) - mu * mu;
  float rstd = rsqrtf(var + 1e-5f);
  short4v o;
  o[0] = f2bf((f0 - mu) * rstd * g[k] + b[k]);
  o[1] = f2bf((f1 - mu) * rstd * g[k + 1] + b[k + 1]);
  o[2] = f2bf((f2 - mu) * rstd * g[k + 2] + b[k + 2]);
  o[3] = f2bf((f3 - mu) * rstd * g[k + 3] + b[k + 3]);
  *(short4v*)(out + (long)row * CD + k) = o;
}

extern "C" void kernel_launch(void* const* d_in, const int* in_sizes, int n_in,
                              void* d_out, int out_size, void* d_ws, size_t ws_size,
                              hipStream_t stream) {
  const float* x = (const float*)d_in[0];
  const int* q4 = (const int*)d_in[1];
  const float* nrm = (const float*)d_in[2];
  const float* la = (const float*)d_in[3];
  const float* lb = (const float*)d_in[4];
  const float* lng = (const float*)d_in[5];
  const float* lnb = (const float*)d_in[6];

  short* Wb = (short*)d_ws;                             // 24 MB: 12 x [1024][1024] bf16
  short* buf0 = (short*)((char*)d_ws + (24u << 20));    // 8 MB
  short* buf1 = buf0 + (long)NB * CD;                   // 8 MB
  short* buf2 = (short*)d_out;                          // d_out lower 8 MB as bf16 scratch
  short* buf3 = buf2 + (long)NB * CD;                   // d_out upper 8 MB
  float* outf = (float*)d_out;

  prep_kernel<<<dim3(8192), dim3(256), 0, stream>>>(x, buf0, q4, nrm, la, lb, Wb);

  dim3 gg(512), bb(256);
  auto Wl = [&](int l) { return Wb + ((long)l << 20); };

  // block 1 (input xb = buf0, resid buf0)
  qgemm<0><<<gg, bb, 0, stream>>>(buf0, Wl(0), nullptr, buf1);
  qgemm<0><<<gg, bb, 0, stream>>>(buf1, Wl(1), nullptr, buf2);
  qgemm<2><<<gg, bb, 0, stream>>>(buf2, Wl(2), buf0, buf3);
  ln_kernel<<<dim3(4096), dim3(256), 0, stream>>>(buf3, buf0, lng, lnb);
  // block 2 (input/resid buf0)
  qgemm<0><<<gg, bb, 0, stream>>>(buf0, Wl(3), nullptr, buf1);
  qgemm<0><<<gg, bb, 0, stream>>>(buf1, Wl(4), nullptr, buf2);
  qgemm<2><<<gg, bb, 0, stream>>>(buf2, Wl(5), buf0, buf3);
  // block 3 (input/resid buf3)
  qgemm<0><<<gg, bb, 0, stream>>>(buf3, Wl(6), nullptr, buf1);
  qgemm<0><<<gg, bb, 0, stream>>>(buf1, Wl(7), nullptr, buf2);
  qgemm<2><<<gg, bb, 0, stream>>>(buf2, Wl(8), buf3, buf0);
  ln_kernel<<<dim3(4096), dim3(256), 0, stream>>>(buf0, buf1, lng + CD, lnb + CD);
  // block 4 (input/resid buf1), final layer writes f32 to d_out
  qgemm<0><<<gg, bb, 0, stream>>>(buf1, Wl(9), nullptr, buf2);
  qgemm<0><<<gg, bb, 0, stream>>>(buf2, Wl(10), nullptr, buf0);
  qgemm<3><<<gg, bb, 0, stream>>>(buf0, Wl(11), buf1, (void*)outf);
}

// Round 7
// 278.871 us; speedup vs baseline: 2.0313x; 1.1384x over previous
//
#include <hip/hip_runtime.h>

#define CD 1024
#define NB 4096

typedef __attribute__((ext_vector_type(8))) short short8;
typedef __attribute__((ext_vector_type(4))) short short4v;
typedef __attribute__((ext_vector_type(4))) float f32x4;
typedef __attribute__((ext_vector_type(4))) int int4v;

typedef __attribute__((address_space(1))) const void gv_t;
typedef __attribute__((address_space(3))) void lv_t;
#define GLOAD16(g, l) __builtin_amdgcn_global_load_lds((gv_t*)(g), (lv_t*)(l), 16, 0, 0)

__device__ __forceinline__ short f2bf(float f) {
  unsigned u = __float_as_uint(f);
  u = (u + 0x7FFFu + ((u >> 16) & 1u)) >> 16;
  return (short)u;
}
__device__ __forceinline__ float bf2f(short s) {
  return __uint_as_float(((unsigned)(unsigned short)s) << 16);
}

// ---- fused: x f32->bf16 (blocks 0..2047) + dequant12+LoRA-fold (blocks 2048..8191) ----
__global__ __launch_bounds__(256) void prep_kernel(const float* __restrict__ x,
                                                   short* __restrict__ xb,
                                                   const int* __restrict__ q4,
                                                   const float* __restrict__ nrm,
                                                   const float* __restrict__ la,
                                                   const float* __restrict__ lb,
                                                   short* __restrict__ Wb) {
  int bid = blockIdx.x;
  if (bid < 2048) {
    int i = (bid * 256 + threadIdx.x) * 8;
    f32x4 a = *(const f32x4*)(x + i);
    f32x4 b = *(const f32x4*)(x + i + 4);
    short8 o;
    o[0] = f2bf(a[0]); o[1] = f2bf(a[1]); o[2] = f2bf(a[2]); o[3] = f2bf(a[3]);
    o[4] = f2bf(b[0]); o[5] = f2bf(b[1]); o[6] = f2bf(b[2]); o[7] = f2bf(b[3]);
    *(short8*)(xb + i) = o;
    return;
  }
  int tidg = (bid - 2048) * 256 + threadIdx.x;
  int w0 = tidg * 4;
  int l = w0 >> 19;
  int wl = w0 & 524287;
  int g = wl >> 6;
  int j0 = wl & 63;
  int o = g >> 3;
  int kb = ((g & 7) << 7) + (j0 << 1);
  int4v q = *(const int4v*)(q4 + w0);
  float n = nrm[(l << 13) + g];
  float s = n * (2.0f / 15.0f);
  f32x4 B = *(const f32x4*)(lb + (((l << 10) + o) << 2));
  const float* A = la + (l << 12);
  float Ar[4][8];
#pragma unroll
  for (int r = 0; r < 4; ++r) {
    f32x4 u = *(const f32x4*)(A + r * CD + kb);
    f32x4 v = *(const f32x4*)(A + r * CD + kb + 4);
    Ar[r][0] = u[0]; Ar[r][1] = u[1]; Ar[r][2] = u[2]; Ar[r][3] = u[3];
    Ar[r][4] = v[0]; Ar[r][5] = v[1]; Ar[r][6] = v[2]; Ar[r][7] = v[3];
  }
  short8 outv;
#pragma unroll
  for (int p = 0; p < 8; ++p) {
    int qw = q[p >> 1];
    int nib = (qw >> ((p & 1) << 2)) & 15;
    float wv = (float)nib * s - n;
    wv += B[0] * Ar[0][p] + B[1] * Ar[1][p] + B[2] * Ar[2][p] + B[3] * Ar[3][p];
    outv[p] = f2bf(wv);
  }
  *(short8*)(Wb + (l << 20) + (o << 10) + kb) = outv;
}

// ---- GEMM: out[M,O] = Act[M,K] @ W[O,K]^T, bf16 in, f32 acc ----
// BM=BN=128, BK=128 (two 64-k halves, each with R1's proven conflict-free
// layout+swizzle). 512 thr = 8 waves (2/SIMD), wave-tile 64x32. 8 K-steps
// (half the barrier drains of R1). LDS 128 KB dbuf, 1 block/CU, grid 256,
// XCD 4x8 patch map. EPI: 0 = relu->bf16, 2 = +resid->bf16, 3 = +resid->f32
template <int EPI>
__global__ __launch_bounds__(512) void qgemm(const short* __restrict__ Act,
                                             const short* __restrict__ W,
                                             const short* __restrict__ Res,
                                             void* __restrict__ Out) {
  __shared__ __align__(16) short ldsA[2][2][128 * 64];  // [buf][half][row][k]
  __shared__ __align__(16) short ldsB[2][2][128 * 64];
  const int tid = threadIdx.x;
  const int lane = tid & 63;
  const int wid = tid >> 6;
  const int wr = wid >> 2;                 // 0..1 : 64-row slice
  const int wc = wid & 3;                  // 0..3 : 32-col slice
  const int f = blockIdx.x;
  const int xcd = f & 7, c = f >> 3;
  const int m0 = (((xcd << 2) | (c & 3)) << 7);  // 32 M-tiles
  const int o0 = ((c >> 2) << 7);                // 8 O-tiles

  // staging sources: per half h, index i: chunk c = tid + i*512 covers
  // [128 rows][8 chunks]; source pre-swizzled ch ^= row&7; LDS dest linear.
  const short* aptr[2][2];
  const short* bptr[2][2];
#pragma unroll
  for (int h = 0; h < 2; ++h)
#pragma unroll
    for (int i = 0; i < 2; ++i) {
      int cc = tid + (i << 9);
      int row = cc >> 3;
      int ch = (cc & 7) ^ (row & 7);
      aptr[h][i] = Act + (long)(m0 + row) * CD + (h << 6) + (ch << 3);
      bptr[h][i] = W + (long)(o0 + row) * CD + (h << 6) + (ch << 3);
    }

  auto stage = [&](int t, int buf) {
    const int koff = t << 7;
#pragma unroll
    for (int h = 0; h < 2; ++h)
#pragma unroll
      for (int i = 0; i < 2; ++i) {
        GLOAD16(aptr[h][i] + koff, &ldsA[buf][h][(tid + (i << 9)) << 3]);
        GLOAD16(bptr[h][i] + koff, &ldsB[buf][h][(tid + (i << 9)) << 3]);
      }
  };

  f32x4 acc[4][2] = {};
  const int frow = lane & 15;
  const int fch = lane >> 4;               // 0..3
  const int fsw = lane & 7;

  stage(0, 0);
  for (int t = 0; t < 8; ++t) {
    __syncthreads();                       // buf[t&1] staged (drains vmcnt)
    if (t < 7) stage(t + 1, (t + 1) & 1);
#pragma unroll
    for (int kk = 0; kk < 4; ++kk) {
      const short* La = ldsA[t & 1][kk >> 1];
      const short* Lb = ldsB[t & 1][kk >> 1];
      const int chsw = (((kk & 1) << 2) + fch) ^ fsw;
      short8 af[4], wf[2];
#pragma unroll
      for (int m = 0; m < 4; ++m) {
        int row = (wr << 6) + (m << 4) + frow;
        af[m] = *(const short8*)(La + (row << 6) + (chsw << 3));
      }
#pragma unroll
      for (int n = 0; n < 2; ++n) {
        int row = (wc << 5) + (n << 4) + frow;
        wf[n] = *(const short8*)(Lb + (row << 6) + (chsw << 3));
      }
#pragma unroll
      for (int m = 0; m < 4; ++m)
#pragma unroll
        for (int n = 0; n < 2; ++n)
          acc[m][n] = __builtin_amdgcn_mfma_f32_16x16x32_bf16(wf[n], af[m], acc[m][n], 0, 0, 0);
    }
  }

  // epilogue (swapped operands): lane&15 = M-row, (lane>>4)*4+reg = out-col
  const int orow = m0 + (wr << 6) + frow;
  const int ocol = o0 + (wc << 5) + (fch << 2);
#pragma unroll
  for (int m = 0; m < 4; ++m) {
#pragma unroll
    for (int n = 0; n < 2; ++n) {
      long row = orow + (m << 4);
      int col = ocol + (n << 4);
      f32x4 v = acc[m][n];
      if (EPI == 0) {
        short4v ov;
        ov[0] = f2bf(fmaxf(v[0], 0.0f));
        ov[1] = f2bf(fmaxf(v[1], 0.0f));
        ov[2] = f2bf(fmaxf(v[2], 0.0f));
        ov[3] = f2bf(fmaxf(v[3], 0.0f));
        *(short4v*)((short*)Out + row * CD + col) = ov;
      } else if (EPI == 2) {
        short4v rv = *(const short4v*)(Res + row * CD + col);
        short4v ov;
        ov[0] = f2bf(v[0] + bf2f(rv[0]));
        ov[1] = f2bf(v[1] + bf2f(rv[1]));
        ov[2] = f2bf(v[2] + bf2f(rv[2]));
        ov[3] = f2bf(v[3] + bf2f(rv[3]));
        *(short4v*)((short*)Out + row * CD + col) = ov;
      } else {
        short4v rv = *(const short4v*)(Res + row * CD + col);
        f32x4 ov;
        ov[0] = v[0] + bf2f(rv[0]);
        ov[1] = v[1] + bf2f(rv[1]);
        ov[2] = v[2] + bf2f(rv[2]);
        ov[3] = v[3] + bf2f(rv[3]);
        *(f32x4*)((float*)Out + row * CD + col) = ov;
      }
    }
  }
}

// ---- LayerNorm over rows of 1024 bf16 ----
__global__ __launch_bounds__(256) void ln_kernel(const short* __restrict__ in,
                                                 short* __restrict__ out,
                                                 const float* __restrict__ g,
                                                 const float* __restrict__ b) {
  __shared__ float rs_[4], rq_[4];
  int row = blockIdx.x, tid = threadIdx.x;
  int k = tid * 4;
  short4v v = *(const short4v*)(in + (long)row * CD + k);
  float f0 = bf2f(v[0]), f1 = bf2f(v[1]), f2 = bf2f(v[2]), f3 = bf2f(v[3]);
  float s = f0 + f1 + f2 + f3;
  float q = f0 * f0 + f1 * f1 + f2 * f2 + f3 * f3;
#pragma unroll
  for (int off = 1; off < 64; off <<= 1) {
    s += __shfl_xor(s, off);
    q += __shfl_xor(q, off);
  }
  if ((tid & 63) == 0) { rs_[tid >> 6] = s; rq_[tid >> 6] = q; }
  __syncthreads();
  s = rs_[0] + rs_[1] + rs_[2] + rs_[3];
  q = rq_[0] + rq_[1] + rq_[2] + rq_[3];
  float mu = s * (1.0f / 1024.0f);
  float var = q * (1.0f / 1024.0f) - mu * mu;
  float rstd = rsqrtf(var + 1e-5f);
  short4v o;
  o[0] = f2bf((f0 - mu) * rstd * g[k] + b[k]);
  o[1] = f2bf((f1 - mu) * rstd * g[k + 1] + b[k + 1]);
  o[2] = f2bf((f2 - mu) * rstd * g[k + 2] + b[k + 2]);
  o[3] = f2bf((f3 - mu) * rstd * g[k + 3] + b[k + 3]);
  *(short4v*)(out + (long)row * CD + k) = o;
}

extern "C" void kernel_launch(void* const* d_in, const int* in_sizes, int n_in,
                              void* d_out, int out_size, void* d_ws, size_t ws_size,
                              hipStream_t stream) {
  const float* x = (const float*)d_in[0];
  const int* q4 = (const int*)d_in[1];
  const float* nrm = (const float*)d_in[2];
  const float* la = (const float*)d_in[3];
  const float* lb = (const float*)d_in[4];
  const float* lng = (const float*)d_in[5];
  const float* lnb = (const float*)d_in[6];

  short* Wb = (short*)d_ws;                             // 24 MB: 12 x [1024][1024] bf16
  short* buf0 = (short*)((char*)d_ws + (24u << 20));    // 8 MB
  short* buf1 = buf0 + (long)NB * CD;                   // 8 MB
  short* buf2 = (short*)d_out;                          // d_out lower 8 MB as bf16 scratch
  short* buf3 = buf2 + (long)NB * CD;                   // d_out upper 8 MB
  float* outf = (float*)d_out;

  prep_kernel<<<dim3(8192), dim3(256), 0, stream>>>(x, buf0, q4, nrm, la, lb, Wb);

  dim3 gg(256), bb(512);
  auto Wl = [&](int l) { return Wb + ((long)l << 20); };

  // block 1 (input xb = buf0, resid buf0)
  qgemm<0><<<gg, bb, 0, stream>>>(buf0, Wl(0), nullptr, buf1);
  qgemm<0><<<gg, bb, 0, stream>>>(buf1, Wl(1), nullptr, buf2);
  qgemm<2><<<gg, bb, 0, stream>>>(buf2, Wl(2), buf0, buf3);
  ln_kernel<<<dim3(4096), dim3(256), 0, stream>>>(buf3, buf0, lng, lnb);
  // block 2 (input/resid buf0)
  qgemm<0><<<gg, bb, 0, stream>>>(buf0, Wl(3), nullptr, buf1);
  qgemm<0><<<gg, bb, 0, stream>>>(buf1, Wl(4), nullptr, buf2);
  qgemm<2><<<gg, bb, 0, stream>>>(buf2, Wl(5), buf0, buf3);
  // block 3 (input/resid buf3)
  qgemm<0><<<gg, bb, 0, stream>>>(buf3, Wl(6), nullptr, buf1);
  qgemm<0><<<gg, bb, 0, stream>>>(buf1, Wl(7), nullptr, buf2);
  qgemm<2><<<gg, bb, 0, stream>>>(buf2, Wl(8), buf3, buf0);
  ln_kernel<<<dim3(4096), dim3(256), 0, stream>>>(buf0, buf1, lng + CD, lnb + CD);
  // block 4 (input/resid buf1), final layer writes f32 to d_out
  qgemm<0><<<gg, bb, 0, stream>>>(buf1, Wl(9), nullptr, buf2);
  qgemm<0><<<gg, bb, 0, stream>>>(buf2, Wl(10), nullptr, buf0);
  qgemm<3><<<gg, bb, 0, stream>>>(buf0, Wl(11), buf1, (void*)outf);
}